// Round 10
// baseline (546.520 us; speedup 1.0000x reference)
//
#include <hip/hip_runtime.h>
#include <hip/hip_bf16.h>
#include <hip/hip_fp16.h>

#define N 8192
#define FIN 256
#define HD 256
#define LEAKY 0.2f

typedef short sh8 __attribute__((ext_vector_type(8)));       // bf16x8 MFMA fragment
typedef _Float16 h8 __attribute__((ext_vector_type(8)));     // f16x8 MFMA fragment
typedef _Float16 h2 __attribute__((ext_vector_type(2)));
typedef float f32x4 __attribute__((ext_vector_type(4)));
typedef int   i32x4 __attribute__((ext_vector_type(4)));

__device__ __forceinline__ int pack2bf(float a, float b){
  __hip_bfloat162 t = __float22bfloat162_rn(make_float2(a, b));
  union { __hip_bfloat162 h; int i; } u;
  u.h = t;
  return u.i;
}

__device__ __forceinline__ h2 u2h2(unsigned u){ union{unsigned u; h2 h;} c; c.u=u; return c.h; }
__device__ __forceinline__ unsigned h22u(h2 h){ union{unsigned u; h2 h;} c; c.h=h; return c.u; }

// ---------------- K0: W (256x256 f32, [k][c]) -> Wt (bf16, [c][k]) ----------------
__global__ void k_wt(const float* __restrict__ W, __hip_bfloat16* __restrict__ Wt){
  __shared__ float t[16][17];
  int tx = threadIdx.x, ty = threadIdx.y;
  int bx = blockIdx.x*16, by = blockIdx.y*16;
  t[ty][tx] = W[(by+ty)*HD + (bx+tx)];
  __syncthreads();
  Wt[(bx+ty)*FIN + (by+tx)] = __float2bfloat16(t[tx][ty]);
}

// ---------------- K_hb: merged  bits-conversion (blocks 0..4095)  +  h/scores -------
// bits: adj (N*N int32) -> u64 bitmask with eye OR'd in (pure HBM stream).
// h (blocks 4096..4351): h_t f16 + El/El2 fp32 + Erh/Er2h f16. Independent inputs ->
// the two phases overlap in one launch instead of running serially.
__global__ __launch_bounds__(256, 2) void k_hb(
    const float* __restrict__ x, const __hip_bfloat16* __restrict__ Wt,
    const float* __restrict__ a_l, const float* __restrict__ a_r,
    const int* __restrict__ adj,
    _Float16* __restrict__ ht, float* __restrict__ El, float* __restrict__ El2,
    _Float16* __restrict__ Erh, _Float16* __restrict__ Er2h,
    unsigned long long* __restrict__ bits)
{
  if (blockIdx.x < 4096){
    // ---- bits path ----
    const int lane = threadIdx.x & 63;
    const int wid = (blockIdx.x*256 + threadIdx.x) >> 6;
    const int nw = (4096*256) >> 6;
    const int total = (N/64)*N;                          // idx = r*128 + c
    for (int idx = wid; idx < total; idx += nw){
      const int r = idx >> 7, c = idx & 127;
      int av = __builtin_nontemporal_load(adj + (size_t)r*N + c*64 + lane);
      unsigned long long b = __ballot(av != 0);
      if (c == (r >> 6)) b |= 1ull << (r & 63);          // + eye
      if (lane == 0) bits[idx] = b;
    }
    return;
  }

  // ---- h path ----
  const int lane = threadIdx.x & 63;
  const int w = threadIdx.x >> 6;      // c-group == head
  const int r0 = lane & 15, q = lane >> 4;
  const int c0 = w*64;
  const int n0 = (blockIdx.x - 4096)*32;

  f32x4 acc[4][2];
  #pragma unroll
  for (int m = 0; m < 4; ++m)
    #pragma unroll
    for (int nt = 0; nt < 2; ++nt)
      acc[m][nt] = (f32x4){0.f, 0.f, 0.f, 0.f};

  for (int kb = 0; kb < 8; ++kb){
    const int k = kb*32 + q*8;
    sh8 af[4];
    #pragma unroll
    for (int m = 0; m < 4; ++m)
      af[m] = *(const sh8*)(Wt + (c0 + m*16 + r0)*FIN + k);
    #pragma unroll
    for (int nt = 0; nt < 2; ++nt){
      const float* xp = x + (n0 + nt*16 + r0)*FIN + k;
      f32x4 xl = *(const f32x4*)xp;
      f32x4 xh = *(const f32x4*)(xp + 4);
      union { sh8 s; int i[4]; } bx;
      bx.i[0] = pack2bf(xl[0], xl[1]);
      bx.i[1] = pack2bf(xl[2], xl[3]);
      bx.i[2] = pack2bf(xh[0], xh[1]);
      bx.i[3] = pack2bf(xh[2], xh[3]);
      #pragma unroll
      for (int m = 0; m < 4; ++m)
        acc[m][nt] = __builtin_amdgcn_mfma_f32_16x16x32_bf16(af[m], bx.s, acc[m][nt], 0, 0, 0);
    }
  }

  float pl[2] = {0.f, 0.f}, pr[2] = {0.f, 0.f};
  #pragma unroll
  for (int m = 0; m < 4; ++m){
    #pragma unroll
    for (int reg = 0; reg < 4; ++reg){
      const int c = c0 + m*16 + q*4 + reg;      // C row = q*4+reg
      const float alv = a_l[c], arv = a_r[c];
      #pragma unroll
      for (int nt = 0; nt < 2; ++nt){
        float v = acc[m][nt][reg];
        ht[(size_t)c*N + (n0 + nt*16 + r0)] = (_Float16)v;  // C col = r0
        pl[nt] += v*alv;
        pr[nt] += v*arv;
      }
    }
  }
  #pragma unroll
  for (int nt = 0; nt < 2; ++nt){
    pl[nt] += __shfl_xor(pl[nt], 16); pl[nt] += __shfl_xor(pl[nt], 32);
    pr[nt] += __shfl_xor(pr[nt], 16); pr[nt] += __shfl_xor(pr[nt], 32);
  }
  if (lane < 16){
    #pragma unroll
    for (int nt = 0; nt < 2; ++nt){
      const int n = n0 + nt*16 + r0;
      const float l = pl[nt], r = pr[nt];
      El  [w*N + n] = __expf(l);
      El2 [w*N + n] = __expf(LEAKY*l);
      Erh [w*N + n] = (_Float16)__expf(r);
      Er2h[w*N + n] = (_Float16)__expf(LEAKY*r);
    }
  }
}

// ---------------- K2: barrier-free attention, direct output ------------------------
// grid 1024: b = h*256 + i32idx. Block owns 32 i-rows, one head. Wave w owns the
// FULL j-quarter w*2048 (64 windows of 32 j) for all 32 rows -> the 4 j-partials
// live in one block; no cross-block `part`, no k_out.
// Each wave double-buffers its PRIVATE 4 KB ht window (global_load_lds into its own
// LDS region) -> no __syncthreads in the loop; per-wave s_waitcnt vmcnt(4) instead.
// Issue order per iter (pinned): [bits+er loads] [4x stage] [vmcnt(4)] [ds_read, compute]
// -> FIFO drains prev window + body loads while this iter's stage stays in flight.
__global__ __launch_bounds__(256, 4) void k_attn(
    const unsigned* __restrict__ bits32, const _Float16* __restrict__ ht,
    const float* __restrict__ El, const float* __restrict__ El2,
    const _Float16* __restrict__ Erh, const _Float16* __restrict__ Er2h,
    float* __restrict__ out)
{
  __shared__ __align__(16) char smem[33280];    // 4 waves x (2 x 4 KB) + 512 B z
  const int b = blockIdx.x;
  const int h = b >> 8;                          // 0..3
  const int i0 = (b & 255) * 32;                 // 32-row base
  const int tid = threadIdx.x;
  const int lane = tid & 63;
  const int w = tid >> 6;                        // j-quarter index
  const int r0 = lane & 15, q = lane >> 4;
  const int jbase = w * 2048;

  // staging: instr s covers feats s*16 + (lane>>2); LDS slot (lane&3) holds global
  // j-chunk (lane&3)^((lane>>3)&3) (bank-deconflict swizzle, round-7 verified).
  const _Float16* gp = ht + (size_t)(h*64 + (lane >> 2))*N
                          + jbase + (((lane & 3) ^ ((lane >> 3) & 3))*8);
  char* lb = smem + w*8192;
  // fragment read: feat f = d*16+r0, slot q^((r0>>1)&3) -> global chunk q
  const char* frp = smem + w*8192 + r0*64 + ((q ^ ((r0 >> 1) & 3)) << 4);

  h2 elh[2], el2h[2];
  #pragma unroll
  for (int m = 0; m < 2; ++m){
    _Float16 a = (_Float16)El [h*N + i0 + m*16 + r0];
    _Float16 c = (_Float16)El2[h*N + i0 + m*16 + r0];
    elh[m]  = (h2){a, a};
    el2h[m] = (h2){c, c};
  }
  const unsigned* bp0 = bits32 + (size_t)(i0 + r0)*(N/32) + w*64;
  const unsigned* bp1 = bp0 + 16*(N/32);
  const _Float16* erq  = Erh  + h*N + jbase + q*8;
  const _Float16* er2q = Er2h + h*N + jbase + q*8;

  union { h8 s; int i[4]; } onef;
  {
    int v = (r0 == 0) ? 0x3C003C00 : 0;          // f16 1.0 pair in col 0
    onef.i[0]=v; onef.i[1]=v; onef.i[2]=v; onef.i[3]=v;
  }

  f32x4 acc[2][4];
  f32x4 accz[2];
  #pragma unroll
  for (int m = 0; m < 2; ++m){
    accz[m] = (f32x4){0.f,0.f,0.f,0.f};
    #pragma unroll
    for (int d = 0; d < 4; ++d)
      acc[m][d] = (f32x4){0.f,0.f,0.f,0.f};
  }

#define STAGE(bufoff, t) do { \
    const _Float16* _g = gp + (t)*32; \
    _Pragma("unroll") \
    for (int _s = 0; _s < 4; ++_s) \
      __builtin_amdgcn_global_load_lds( \
        (const __attribute__((address_space(1))) void*)(_g + _s*16*N), \
        (__attribute__((address_space(3))) void*)(lb + (bufoff) + _s*1024), 16, 0, 0); \
  } while(0)

  STAGE(0, 0);                                   // window 0 -> buf0 (no barrier!)

  #pragma unroll 2
  for (int t = 0; t < 64; ++t){
    const int bo = (t & 1) ? 4096 : 0;
    const int bn = bo ^ 4096;
    const int tn = (t < 63) ? t + 1 : 63;        // tail reload harmless

    // body-consumed vmem FIRST (older than stage in the vmcnt FIFO)
    unsigned bw0 = bp0[t];
    unsigned bw1 = bp1[t];
    i32x4 er4  = *(const i32x4*)(erq  + t*32);
    i32x4 er24 = *(const i32x4*)(er2q + t*32);
    __builtin_amdgcn_sched_barrier(0);
    STAGE(bn, tn);                               // next window -> other buffer
    __builtin_amdgcn_sched_barrier(0);
    __builtin_amdgcn_s_waitcnt(0x0F74);          // vmcnt(4): prev window + body drained
    __builtin_amdgcn_sched_barrier(0);

    h8 hf[4];
    #pragma unroll
    for (int d = 0; d < 4; ++d)
      hf[d] = *(const h8*)(frp + bo + d*1024);   // ds_read_b128, conflict-free

    #pragma unroll
    for (int m = 0; m < 2; ++m){
      const unsigned sw = ((m == 0) ? bw0 : bw1) >> (q*8);
      unsigned fu[4];
      #pragma unroll
      for (int p = 0; p < 4; ++p){
        h2 w2 = __builtin_elementwise_max(elh[m]  * u2h2((unsigned)er4[p]),
                                          el2h[m] * u2h2((unsigned)er24[p]));
        unsigned lo = (sw >> (2*p)) & 1u;
        unsigned hi = (sw >> (2*p+1)) & 1u;
        unsigned msk = lo*0xFFFFu + hi*0xFFFF0000u;
        fu[p] = h22u(w2) & msk;
      }
      union { h8 s; unsigned u[4]; } fa;
      fa.u[0]=fu[0]; fa.u[1]=fu[1]; fa.u[2]=fu[2]; fa.u[3]=fu[3];
      #pragma unroll
      for (int d = 0; d < 4; ++d)
        acc[m][d] = __builtin_amdgcn_mfma_f32_16x16x32_f16(fa.s, hf[d], acc[m][d], 0, 0, 0);
      accz[m] = __builtin_amdgcn_mfma_f32_16x16x32_f16(fa.s, onef.s, accz[m], 0, 0, 0);
    }
  }
#undef STAGE

  // ---- epilogue: intra-block reduce over the 4 j-quarters, divide, store out ----
  __builtin_amdgcn_s_waitcnt(0x0F70);            // vmcnt(0): all DMA retired before
  __builtin_amdgcn_sched_barrier(0);             // we overwrite the staging region

  // partials [row32][col64] f32 in this wave's 8 KB region
  float* prg = (float*)(smem + w*8192);
  #pragma unroll
  for (int m = 0; m < 2; ++m)
    #pragma unroll
    for (int d = 0; d < 4; ++d)
      #pragma unroll
      for (int reg = 0; reg < 4; ++reg)
        prg[(m*16 + q*4 + reg)*64 + d*16 + r0] = acc[m][d][reg];
  if (r0 == 0){
    float* zr = (float*)(smem + 32768 + w*128);
    #pragma unroll
    for (int m = 0; m < 2; ++m)
      *(f32x4*)(zr + m*16 + q*4) = accz[m];
  }
  __syncthreads();

  const int r  = tid >> 3;                       // 0..31
  const int c8 = (tid & 7) * 8;                  // 0..56
  f32x4 s0 = (f32x4){0.f,0.f,0.f,0.f}, s1 = (f32x4){0.f,0.f,0.f,0.f};
  float zz = 0.f;
  #pragma unroll
  for (int w4 = 0; w4 < 4; ++w4){
    const float* p2 = (const float*)(smem + w4*8192) + r*64 + c8;
    s0 += *(const f32x4*)p2;
    s1 += *(const f32x4*)(p2 + 4);
    zz += ((const float*)(smem + 32768 + w4*128))[r];
  }
  float* op = out + (size_t)(i0 + r)*HD + h*64 + c8;
  *(f32x4*)op       = s0 / zz;
  *(f32x4*)(op + 4) = s1 / zz;
}

extern "C" void kernel_launch(void* const* d_in, const int* in_sizes, int n_in,
                              void* d_out, int out_size, void* d_ws, size_t ws_size,
                              hipStream_t stream) {
  const float* x   = (const float*)d_in[0];
  const int*   adj = (const int*)d_in[1];
  const float* W   = (const float*)d_in[2];
  const float* a_l = (const float*)d_in[3];
  const float* a_r = (const float*)d_in[4];
  float* out = (float*)d_out;

  char* ws = (char*)d_ws;
  __hip_bfloat16* Wt = (__hip_bfloat16*)ws;                     // 128 KB
  _Float16* ht   = (_Float16*)(ws + 131072);                    // 4 MB
  float*    El   = (float*)   (ws + 4325376);                   // 128 KB
  float*    El2  = (float*)   (ws + 4456448);                   // 128 KB
  _Float16* Erh  = (_Float16*)(ws + 4587520);                   // 64 KB
  _Float16* Er2h = (_Float16*)(ws + 4653056);                   // 64 KB
  unsigned long long* bits = (unsigned long long*)(ws + 4718592); // 8 MB

  k_wt <<<dim3(16,16), dim3(16,16), 0, stream>>>(W, Wt);
  k_hb <<<4352, 256, 0, stream>>>(x, Wt, a_l, a_r, adj, ht, El, El2, Erh, Er2h, bits);
  k_attn<<<1024, 256, 0, stream>>>((const unsigned*)bits, ht, El, El2, Erh, Er2h, out);
}

// Round 11
// 524.624 us; speedup vs baseline: 1.0417x; 1.0417x over previous
//
#include <hip/hip_runtime.h>
#include <hip/hip_bf16.h>
#include <hip/hip_fp16.h>

#define N 8192
#define FIN 256
#define HD 256
#define LEAKY 0.2f

typedef short sh8 __attribute__((ext_vector_type(8)));       // bf16x8 MFMA fragment
typedef _Float16 h8 __attribute__((ext_vector_type(8)));     // f16x8 MFMA fragment
typedef _Float16 h2 __attribute__((ext_vector_type(2)));
typedef float f32x4 __attribute__((ext_vector_type(4)));
typedef int   i32x4 __attribute__((ext_vector_type(4)));

__device__ __forceinline__ int pack2bf(float a, float b){
  __hip_bfloat162 t = __float22bfloat162_rn(make_float2(a, b));
  union { __hip_bfloat162 h; int i; } u;
  u.h = t;
  return u.i;
}

__device__ __forceinline__ h2 u2h2(unsigned u){ union{unsigned u; h2 h;} c; c.u=u; return c.h; }
__device__ __forceinline__ unsigned h22u(h2 h){ union{unsigned u; h2 h;} c; c.h=h; return c.u; }

// ---------------- K0: W (256x256 f32, [k][c]) -> Wt (bf16, [c][k]) ----------------
__global__ void k_wt(const float* __restrict__ W, __hip_bfloat16* __restrict__ Wt){
  __shared__ float t[16][17];
  int tx = threadIdx.x, ty = threadIdx.y;
  int bx = blockIdx.x*16, by = blockIdx.y*16;
  t[ty][tx] = W[(by+ty)*HD + (bx+tx)];
  __syncthreads();
  Wt[(bx+ty)*FIN + (by+tx)] = __float2bfloat16(t[tx][ty]);
}

// ---------------- K_hb: co-dispatched h/scores (blocks 0..255) + bits (256..4351) ---
// h path: ht2 tile-blocked layout [h][T:64][f:64][j:128] f16 with the LDS bank
// swizzle baked in at write (col j ^ (((f>>1)&3)<<3)) -> k_attn staging is LINEAR.
// bits path: adj -> bits2 TRANSPOSED u64 [jword:128][row:8192], eye OR'd in ->
// k_attn mask loads are consecutive dwords (2 lines), not 16-line gathers.
__global__ __launch_bounds__(256, 2) void k_hb(
    const float* __restrict__ x, const __hip_bfloat16* __restrict__ Wt,
    const float* __restrict__ a_l, const float* __restrict__ a_r,
    const int* __restrict__ adj,
    _Float16* __restrict__ ht2, float* __restrict__ El, float* __restrict__ El2,
    _Float16* __restrict__ Erh, _Float16* __restrict__ Er2h,
    unsigned long long* __restrict__ bits2)
{
  if (blockIdx.x >= 256){
    // ---- bits path (transposed store) ----
    const int lane = threadIdx.x & 63;
    const int wid = ((blockIdx.x - 256)*256 + threadIdx.x) >> 6;
    const int nw = (4096*256) >> 6;
    const int total = (N/64)*N;                          // idx = r*128 + c
    for (int idx = wid; idx < total; idx += nw){
      const int r = idx >> 7, c = idx & 127;
      int av = __builtin_nontemporal_load(adj + (size_t)r*N + c*64 + lane);
      unsigned long long b = __ballot(av != 0);
      if (c == (r >> 6)) b |= 1ull << (r & 63);          // + eye
      if (lane == 0) bits2[(size_t)c*N + r] = b;         // [jword][row]
    }
    return;
  }

  // ---- h path ----
  const int lane = threadIdx.x & 63;
  const int w = threadIdx.x >> 6;      // c-group == head
  const int r0 = lane & 15, q = lane >> 4;
  const int c0 = w*64;
  const int n0 = blockIdx.x*32;
  const int T = n0 >> 7;               // j-tile of ht2 (fixed: 32-row block in one T)
  const int jb = n0 & 127;

  f32x4 acc[4][2];
  #pragma unroll
  for (int m = 0; m < 4; ++m)
    #pragma unroll
    for (int nt = 0; nt < 2; ++nt)
      acc[m][nt] = (f32x4){0.f, 0.f, 0.f, 0.f};

  for (int kb = 0; kb < 8; ++kb){
    const int k = kb*32 + q*8;
    sh8 af[4];
    #pragma unroll
    for (int m = 0; m < 4; ++m)
      af[m] = *(const sh8*)(Wt + (c0 + m*16 + r0)*FIN + k);
    #pragma unroll
    for (int nt = 0; nt < 2; ++nt){
      const float* xp = x + (n0 + nt*16 + r0)*FIN + k;
      f32x4 xl = *(const f32x4*)xp;
      f32x4 xh = *(const f32x4*)(xp + 4);
      union { sh8 s; int i[4]; } bx;
      bx.i[0] = pack2bf(xl[0], xl[1]);
      bx.i[1] = pack2bf(xl[2], xl[3]);
      bx.i[2] = pack2bf(xh[0], xh[1]);
      bx.i[3] = pack2bf(xh[2], xh[3]);
      #pragma unroll
      for (int m = 0; m < 4; ++m)
        acc[m][nt] = __builtin_amdgcn_mfma_f32_16x16x32_bf16(af[m], bx.s, acc[m][nt], 0, 0, 0);
    }
  }

  _Float16* htb = ht2 + (size_t)(w*64 + T)*8192;   // this (head, T) 16 KB block
  float pl[2] = {0.f, 0.f}, pr[2] = {0.f, 0.f};
  #pragma unroll
  for (int m = 0; m < 4; ++m){
    #pragma unroll
    for (int reg = 0; reg < 4; ++reg){
      const int f = m*16 + q*4 + reg;           // head-local feature (C row)
      const float alv = a_l[c0 + f], arv = a_r[c0 + f];
      const int sw = ((f >> 1) & 3) << 3;       // baked LDS swizzle
      #pragma unroll
      for (int nt = 0; nt < 2; ++nt){
        float v = acc[m][nt][reg];
        const int jj = jb + nt*16 + r0;         // C col = r0
        htb[f*128 + (jj ^ sw)] = (_Float16)v;
        pl[nt] += v*alv;
        pr[nt] += v*arv;
      }
    }
  }
  #pragma unroll
  for (int nt = 0; nt < 2; ++nt){
    pl[nt] += __shfl_xor(pl[nt], 16); pl[nt] += __shfl_xor(pl[nt], 32);
    pr[nt] += __shfl_xor(pr[nt], 16); pr[nt] += __shfl_xor(pr[nt], 32);
  }
  if (lane < 16){
    #pragma unroll
    for (int nt = 0; nt < 2; ++nt){
      const int n = n0 + nt*16 + r0;
      const float l = pl[nt], r = pr[nt];
      El  [w*N + n] = __expf(l);
      El2 [w*N + n] = __expf(LEAKY*l);
      Erh [w*N + n] = (_Float16)__expf(r);
      Er2h[w*N + n] = (_Float16)__expf(LEAKY*r);
    }
  }
}

// ---------------- K2: attention, all-linear loads, direct output --------------------
// grid 1024: b = h*256 + i32idx. Block owns 32 i-rows, one head, sweeps ALL j in
// 64 tiles of 128 j. Shared LDS staging (R7 barrier structure, proven): per tile,
// each wave stages 4 KB LINEARLY from ht2 (16 sequential lines per instruction);
// wave w computes only its own 32-j subtile -> 4 j-partials live in one block ->
// no part buffer, no k_out. Mask from transposed bits2: 2 consecutive dwords/tile.
__global__ __launch_bounds__(256, 4) void k_attn(
    const unsigned* __restrict__ b32, const _Float16* __restrict__ ht2,
    const float* __restrict__ El, const float* __restrict__ El2,
    const _Float16* __restrict__ Erh, const _Float16* __restrict__ Er2h,
    float* __restrict__ out)
{
  __shared__ __align__(16) char smem[33280];    // 2 x 16 KB tile buffers + 512 B z
  const int b = blockIdx.x;
  const int h = b >> 8;                          // 0..3
  const int i0 = (b & 255) * 32;                 // 32-row base
  const int tid = threadIdx.x;
  const int lane = tid & 63;
  const int w = tid >> 6;                        // j-subtile owner (32 j of each 128)
  const int r0 = lane & 15, q = lane >> 4;

  // linear staging: wave w covers tile bytes [w*4KB, w*4KB+4KB), instr _s 1 KB each
  const _Float16* gp = ht2 + (size_t)h*64*8192 + w*2048 + lane*8;
  char* lb = smem + w*4096;
  // fragment read (swizzle baked into ht2): f = d*16+r0, slot q^((r0>>1)&3)
  const char* frp = smem + r0*256 + w*64 + ((q ^ ((r0 >> 1) & 3)) << 4);

  h2 elh[2], el2h[2];
  #pragma unroll
  for (int m = 0; m < 2; ++m){
    _Float16 a = (_Float16)El [h*N + i0 + m*16 + r0];
    _Float16 c = (_Float16)El2[h*N + i0 + m*16 + r0];
    elh[m]  = (h2){a, a};
    el2h[m] = (h2){c, c};
  }
  // bits2 u32 view: word (c = t*2 + (w>>1), row, half = w&1) -> consecutive per r0
  const unsigned* bpp = b32 + (size_t)(w >> 1)*16384 + (size_t)(i0 + r0)*2 + (w & 1);
  const _Float16* erq  = Erh  + h*N + w*32 + q*8;
  const _Float16* er2q = Er2h + h*N + w*32 + q*8;

  union { h8 s; int i[4]; } onef;
  {
    int v = (r0 == 0) ? 0x3C003C00 : 0;          // f16 1.0 pair in col 0
    onef.i[0]=v; onef.i[1]=v; onef.i[2]=v; onef.i[3]=v;
  }

  f32x4 acc[2][4];
  f32x4 accz[2];
  #pragma unroll
  for (int m = 0; m < 2; ++m){
    accz[m] = (f32x4){0.f,0.f,0.f,0.f};
    #pragma unroll
    for (int d = 0; d < 4; ++d)
      acc[m][d] = (f32x4){0.f,0.f,0.f,0.f};
  }

#define STAGE(bufoff, t) do { \
    const _Float16* _g = gp + (size_t)(t)*8192; \
    _Pragma("unroll") \
    for (int _s = 0; _s < 4; ++_s) \
      __builtin_amdgcn_global_load_lds( \
        (const __attribute__((address_space(1))) void*)(_g + _s*512), \
        (__attribute__((address_space(3))) void*)(lb + (bufoff) + _s*1024), 16, 0, 0); \
  } while(0)

  STAGE(0, 0);
  __syncthreads();                               // tile 0 resident in buf0

  for (int t = 0; t < 64; ++t){
    const int bo = (t & 1) ? 16384 : 0;
    const int bn = bo ^ 16384;
    const int tn = (t + 1) & 63;                 // tail wrap harmless

    unsigned bw0 = bpp[(size_t)t*32768];         // mask, rows m=0 (consecutive dwords)
    unsigned bw1 = bpp[(size_t)t*32768 + 32];    // rows m=1
    i32x4 er4  = *(const i32x4*)(erq  + t*128);
    i32x4 er24 = *(const i32x4*)(er2q + t*128);

    STAGE(bn, tn);                               // next tile -> other buffer (linear)

    h8 hf[4];
    #pragma unroll
    for (int d = 0; d < 4; ++d)
      hf[d] = *(const h8*)(frp + bo + d*4096);   // ds_read_b128, ~conflict-free

    #pragma unroll
    for (int m = 0; m < 2; ++m){
      const unsigned sw = ((m == 0) ? bw0 : bw1) >> (q*8);
      unsigned fu[4];
      #pragma unroll
      for (int p = 0; p < 4; ++p){
        h2 w2 = __builtin_elementwise_max(elh[m]  * u2h2((unsigned)er4[p]),
                                          el2h[m] * u2h2((unsigned)er24[p]));
        unsigned lo = (sw >> (2*p)) & 1u;
        unsigned hi = (sw >> (2*p+1)) & 1u;
        unsigned msk = lo*0xFFFFu + hi*0xFFFF0000u;
        fu[p] = h22u(w2) & msk;
      }
      union { h8 s; unsigned u[4]; } fa;
      fa.u[0]=fu[0]; fa.u[1]=fu[1]; fa.u[2]=fu[2]; fa.u[3]=fu[3];
      #pragma unroll
      for (int d = 0; d < 4; ++d)
        acc[m][d] = __builtin_amdgcn_mfma_f32_16x16x32_f16(fa.s, hf[d], acc[m][d], 0, 0, 0);
      accz[m] = __builtin_amdgcn_mfma_f32_16x16x32_f16(fa.s, onef.s, accz[m], 0, 0, 0);
    }

    __syncthreads();                             // next tile staged; this buf free
  }
#undef STAGE

  // ---- epilogue: reduce the 4 waves' j-partials in LDS, divide, store out ----
  // (final loop __syncthreads drained all DMA; staging region is reusable)
  float* prg = (float*)(smem + w*8192);          // [row32][col64] f32 per wave
  #pragma unroll
  for (int m = 0; m < 2; ++m)
    #pragma unroll
    for (int d = 0; d < 4; ++d)
      #pragma unroll
      for (int reg = 0; reg < 4; ++reg)
        prg[(m*16 + q*4 + reg)*64 + d*16 + r0] = acc[m][d][reg];
  if (r0 == 0){
    float* zr = (float*)(smem + 32768 + w*128);
    #pragma unroll
    for (int m = 0; m < 2; ++m)
      *(f32x4*)(zr + m*16 + q*4) = accz[m];
  }
  __syncthreads();

  const int r  = tid >> 3;                       // 0..31
  const int c8 = (tid & 7) * 8;                  // 0..56
  f32x4 s0 = (f32x4){0.f,0.f,0.f,0.f}, s1 = (f32x4){0.f,0.f,0.f,0.f};
  float zz = 0.f;
  #pragma unroll
  for (int w4 = 0; w4 < 4; ++w4){
    const float* p2 = (const float*)(smem + w4*8192) + r*64 + c8;
    s0 += *(const f32x4*)p2;
    s1 += *(const f32x4*)(p2 + 4);
    zz += ((const float*)(smem + 32768 + w4*128))[r];
  }
  float* op = out + (size_t)(i0 + r)*HD + h*64 + c8;
  *(f32x4*)op       = s0 / zz;
  *(f32x4*)(op + 4) = s1 / zz;
}

extern "C" void kernel_launch(void* const* d_in, const int* in_sizes, int n_in,
                              void* d_out, int out_size, void* d_ws, size_t ws_size,
                              hipStream_t stream) {
  const float* x   = (const float*)d_in[0];
  const int*   adj = (const int*)d_in[1];
  const float* W   = (const float*)d_in[2];
  const float* a_l = (const float*)d_in[3];
  const float* a_r = (const float*)d_in[4];
  float* out = (float*)d_out;

  char* ws = (char*)d_ws;
  __hip_bfloat16* Wt = (__hip_bfloat16*)ws;                     // 128 KB
  _Float16* ht2  = (_Float16*)(ws + 131072);                    // 4 MB (tile-blocked)
  float*    El   = (float*)   (ws + 4325376);                   // 128 KB
  float*    El2  = (float*)   (ws + 4456448);                   // 128 KB
  _Float16* Erh  = (_Float16*)(ws + 4587520);                   // 64 KB
  _Float16* Er2h = (_Float16*)(ws + 4653056);                   // 64 KB
  unsigned long long* bits2 = (unsigned long long*)(ws + 4718592); // 8 MB (transposed)

  k_wt <<<dim3(16,16), dim3(16,16), 0, stream>>>(W, Wt);
  k_hb <<<4352, 256, 0, stream>>>(x, Wt, a_l, a_r, adj, ht2, El, El2, Erh, Er2h, bits2);
  k_attn<<<1024, 256, 0, stream>>>((const unsigned*)bits2, ht2, El, El2, Erh, Er2h, out);
}